// Round 14
// baseline (670.448 us; speedup 1.0000x reference)
//
#include <hip/hip_runtime.h>
#include <cstdint>
#include <cmath>

typedef __bf16 bf16;
typedef __attribute__((ext_vector_type(8))) __bf16 bf16x8;
typedef __attribute__((ext_vector_type(4))) __bf16 bf16x4;
typedef __attribute__((ext_vector_type(2))) __bf16 bf16x2;
typedef __attribute__((ext_vector_type(4))) float f32x4;

constexpr int B_ = 2, T_ = 2048, C_ = 1024, H_ = 16, HD_ = 64;
constexpr int M_ = B_ * T_;   // 4096

#define EXP2F(x) __builtin_amdgcn_exp2f(x)
#define LOG2F(x) __builtin_amdgcn_logf(x)
#define SQRTF(x) __builtin_amdgcn_sqrtf(x)
#define RCPF(x)  __builtin_amdgcn_rcpf(x)

// ---- async global->LDS, 16B per lane; LDS dest = wave-uniform base + lane*16 ----
__device__ __forceinline__ void gld16(const void* g, void* l) {
  __builtin_amdgcn_global_load_lds((const __attribute__((address_space(1))) void*)g,
                                   (__attribute__((address_space(3))) void*)l, 16, 0, 0);
}

// ====  fused weight cast fp32 -> bf16 (w_uv/b_uv row-PERMUTED) + rmsnorm#1 tail  ====
// blocks [0, 16392): casts.  blocks [16392, 16392+4096): rmsnorm rows of x -> hbuf.
constexpr int CAST_BLOCKS = 16392;  // (786432+262144+2097152+1048576+2048)/256
__global__ __launch_bounds__(256) void cast_rms_kernel(const float* __restrict__ s0,
                                                       const float* __restrict__ s1,
                                                       const float* __restrict__ s2,
                                                       const float* __restrict__ s3,
                                                       const float* __restrict__ s4,
                                                       bf16* __restrict__ d0,
                                                       bf16* __restrict__ d1,
                                                       bf16* __restrict__ d2,
                                                       bf16* __restrict__ d3,
                                                       float* __restrict__ d4,
                                                       const float* __restrict__ xin,
                                                       bf16* __restrict__ hout) {
  if (blockIdx.x >= CAST_BLOCKS) {
    // ---- rmsnorm row ----
    const int row = blockIdx.x - CAST_BLOCKS;
    const int tid = threadIdx.x;
    const int wave = tid >> 6;
    f32x4 v = *(const f32x4*)(xin + (size_t)row * C_ + tid * 4);
    float s = v[0] * v[0] + v[1] * v[1] + v[2] * v[2] + v[3] * v[3];
#pragma unroll
    for (int off = 32; off >= 1; off >>= 1) s += __shfl_xor(s, off);
    __shared__ float wsum[4];
    __shared__ float scale_sh;
    if ((tid & 63) == 0) wsum[wave] = s;
    __syncthreads();
    if (tid == 0)
      scale_sh = rsqrtf((wsum[0] + wsum[1] + wsum[2] + wsum[3]) * (1.f / (float)C_) + 1e-6f);
    __syncthreads();
    const float sc = scale_sh;
    bf16x4 o;
    o[0] = (bf16)(v[0] * sc); o[1] = (bf16)(v[1] * sc);
    o[2] = (bf16)(v[2] * sc); o[3] = (bf16)(v[3] * sc);
    *(bf16x4*)(hout + (size_t)row * C_ + tid * 4) = o;
    return;
  }
  size_t gid = (size_t)blockIdx.x * 256 + threadIdx.x;
  if (gid >= 786432 + 262144 + 2097152 + 1048576) {
    size_t g4 = gid - (786432 + 262144 + 2097152 + 1048576);
    if (g4 >= 2048) return;
    int r = (int)(g4 * 4);
    int dr;
    if (r < 4096) { int blk = r >> 6, i = r & 63; dr = blk * 128 + i; }
    else { int j = r - 4096; int blk = j >> 6, i = j & 63; dr = blk * 128 + 64 + i; }
    *(f32x4*)(d4 + dr) = *(const f32x4*)(s4 + r);
    return;
  }
  const float* src;
  bf16* dst;
  size_t dstoff;
  if (gid < 786432) { src = s0; dst = d0; dstoff = gid * 4; }
  else if (gid < 786432 + 262144) { gid -= 786432; src = s1; dst = d1; dstoff = gid * 4; }
  else if (gid < 786432 + 262144 + 2097152) {
    gid -= 786432 + 262144; src = s2; dst = d2;
    size_t elem = gid * 4;
    int r = (int)(elem >> 10), c = (int)(elem & 1023);
    int dr;
    if (r < 4096) { int blk = r >> 6, i = r & 63; dr = blk * 128 + i; }
    else { int j = r - 4096; int blk = j >> 6, i = j & 63; dr = blk * 128 + 64 + i; }
    dstoff = ((size_t)dr << 10) | (size_t)c;
  }
  else { gid -= 786432 + 262144 + 2097152; src = s3; dst = d3; dstoff = gid * 4; }
  f32x4 v = *(const f32x4*)(src + gid * 4);
  bf16x4 o;
  o[0] = (bf16)v[0]; o[1] = (bf16)v[1]; o[2] = (bf16)v[2]; o[3] = (bf16)v[3];
  *(bf16x4*)(dst + dstoff) = o;
}

// =============  GEMM: C = A @ Bw^T (+epilogues), bf16 operands  =============
// BK=64 (two stacked [BM][32] A half-tiles + [128][32] B halves); one barrier pair/64K.
// BM=128: acc 4x4.  BM=64: acc 2x4 -> 2 blocks/CU for N=1024 shapes.
// MODE 0: C=AB  1: +R  2: +bias  3: +bias+R
// MODE 4 (BM=128): swiglu over permuted-uv, in-wave u/v pairing, register-only.
// MODE 5 (BM=128): qkv epilogue — rotary on q/k (in-register pair ntl <-> ntl+2,
//   each wave's 64 cols = one head) + q0/k0 = sqrt(kc+|row|^2) via l16-shuffle reduce.
template <int MODE, typename OutT, int BM = 128>
__global__ __launch_bounds__(256) void gemm_bt(const bf16* __restrict__ A,
                                               const bf16* __restrict__ Bw,
                                               OutT* __restrict__ Cmat,
                                               const float* __restrict__ bias,
                                               const float* __restrict__ R,
                                               float* __restrict__ q0o,
                                               float* __restrict__ k0o,
                                               const float* __restrict__ kcv,
                                               int M, int N, int K, int lda) {
  __shared__ __align__(16) bf16 shmem[(2 * BM + 2 * 128) * 32];
  bf16* const AlsH[2] = { &shmem[0], &shmem[BM * 32] };
  bf16* const BlsH[2] = { &shmem[2 * BM * 32], &shmem[2 * BM * 32 + 4096] };
  const int tid  = threadIdx.x;
  const int wave = tid >> 6;
  const int lane = tid & 63;
  const int quad = lane >> 4;
  const int l16  = lane & 15;
  const int bm = blockIdx.x * BM;
  const int bn = blockIdx.y * 128;
  const int wm = (wave & 1) * (BM / 2);
  const int wn = (wave >> 1) * 64;
  const int wn2 = (wave >> 1) * 32;
  const int srow   = lane >> 2;  // 0..15
  const int schunk = lane & 3;   // 0..3
  constexpr int MT = BM / 32;    // m-tiles per wave

  f32x4 acc[MT][4];
#pragma unroll
  for (int i = 0; i < MT; i++)
#pragma unroll
    for (int j = 0; j < 4; j++) acc[i][j] = f32x4{0.f, 0.f, 0.f, 0.f};

  const bf16* Ag = A  + (size_t)(bm + wave * (BM / 4) + srow) * lda + schunk * 8;
  const bf16* Bg = Bw + (size_t)(bn + wave * 32 + srow) * K   + schunk * 8;
  bf16* AlsW0 = AlsH[0] + (wave * (BM / 4)) * 32;
  bf16* AlsW1 = AlsH[1] + (wave * (BM / 4)) * 32;
  bf16* BlsW0 = BlsH[0] + (wave * 32) * 32;
  bf16* BlsW1 = BlsH[1] + (wave * 32) * 32;

  for (int k0 = 0; k0 < K; k0 += 64) {
    gld16(Ag + k0, AlsW0);
    if (BM == 128) gld16(Ag + k0 + (size_t)16 * lda, AlsW0 + 16 * 32);
    gld16(Ag + k0 + 32, AlsW1);
    if (BM == 128) gld16(Ag + k0 + 32 + (size_t)16 * lda, AlsW1 + 16 * 32);
    gld16(Bg + k0,                       BlsW0);
    gld16(Bg + k0 + (size_t)16 * K,      BlsW0 + 16 * 32);
    gld16(Bg + k0 + 32,                  BlsW1);
    gld16(Bg + k0 + 32 + (size_t)16 * K, BlsW1 + 16 * 32);
    __syncthreads();   // drains vmcnt before barrier

#pragma unroll
    for (int hh = 0; hh < 2; hh++) {
      bf16x8 af[MT], bfr[4];
#pragma unroll
      for (int mt = 0; mt < MT; mt++)
        af[mt] = *(const bf16x8*)&AlsH[hh][(wm + mt * 16 + l16) * 32 + quad * 8];
#pragma unroll
      for (int nt = 0; nt < 4; nt++) {
        const int cb = (MODE == 4)
                         ? ((nt < 2) ? (wn2 + nt * 16) : (64 + wn2 + (nt - 2) * 16))
                         : (wn + nt * 16);
        bfr[nt] = *(const bf16x8*)&BlsH[hh][(cb + l16) * 32 + quad * 8];
      }
#pragma unroll
      for (int mt = 0; mt < MT; mt++)
#pragma unroll
        for (int nt = 0; nt < 4; nt++)
          acc[mt][nt] = __builtin_amdgcn_mfma_f32_16x16x32_bf16(af[mt], bfr[nt], acc[mt][nt], 0, 0, 0);
    }
    __syncthreads();
  }

  if (MODE == 4) {
    // register-only swiglu epilogue: u = acc[mt][ntl], v = acc[mt][ntl+2]
    const int colg0 = (bn >> 1) + wn2;
#pragma unroll
    for (int mt = 0; mt < MT; mt++) {
      const int row = bm + wm + mt * 16 + quad * 4;
#pragma unroll
      for (int ntl = 0; ntl < 2; ntl++) {
        const float bu = bias[bn + wn2 + ntl * 16 + l16];
        const float bv = bias[bn + 64 + wn2 + ntl * 16 + l16];
        const int col = colg0 + ntl * 16 + l16;
#pragma unroll
        for (int r = 0; r < 4; r++) {
          float u = acc[mt][ntl][r] + bu;
          float v = acc[mt][ntl + 2][r] + bv;
          float sig = RCPF(1.f + EXP2F(-v * 1.44269504f));
          Cmat[(size_t)(row + r) * N + col] = (OutT)(u * v * sig);
        }
      }
    }
  } else if (MODE == 5) {
    // qkv epilogue: rotary + q0/k0 for q (cols<1024) and k (cols 1024..2047)
    const int cbase = bn + wn;           // this wave's 64-col span = one head
    if (cbase < 2048) {
      const bool isq = cbase < 1024;
      const int h = (isq ? cbase : cbase - 1024) >> 6;
      const float kc = kcv[h];
      float invf[2];
#pragma unroll
      for (int ntl = 0; ntl < 2; ntl++)
        invf[ntl] = EXP2F(-((float)(ntl * 16 + l16) / 32.f) * 13.287712379549449f);
#pragma unroll
      for (int mt = 0; mt < MT; mt++) {
        float ssl[4] = {0.f, 0.f, 0.f, 0.f};
#pragma unroll
        for (int ntl = 0; ntl < 2; ntl++) {
#pragma unroll
          for (int r = 0; r < 4; r++) {
            const int row = bm + wm + mt * 16 + quad * 4 + r;
            const float ang = (float)(row & 2047) * invf[ntl];
            const float c = cosf(ang), s = sinf(ang);
            const float x1 = acc[mt][ntl][r];
            const float x2 = acc[mt][ntl + 2][r];
            const float o1 = x1 * c + x2 * s;
            const float o2 = x2 * c - x1 * s;
            acc[mt][ntl][r] = o1;
            acc[mt][ntl + 2][r] = o2;
            ssl[r] += o1 * o1 + o2 * o2;
          }
        }
#pragma unroll
        for (int r = 0; r < 4; r++) {
#pragma unroll
          for (int off = 1; off <= 8; off <<= 1) ssl[r] += __shfl_xor(ssl[r], off);
          if (l16 == 0) {
            const int row = bm + wm + mt * 16 + quad * 4 + r;
            float* dst = isq ? q0o : k0o;
            dst[((size_t)((row >> 11) * 16 + h)) * 2048 + (row & 2047)] = SQRTF(kc + ssl[r]);
          }
        }
      }
    }
    // store all cols (rotated or plain v) as bf16
#pragma unroll
    for (int mt = 0; mt < MT; mt++) {
      const int row = bm + wm + mt * 16 + quad * 4;
#pragma unroll
      for (int nt = 0; nt < 4; nt++) {
        const int col = bn + wn + nt * 16 + l16;
#pragma unroll
        for (int r = 0; r < 4; r++)
          Cmat[(size_t)(row + r) * N + col] = (OutT)acc[mt][nt][r];
      }
    }
  } else {
#pragma unroll
    for (int mt = 0; mt < MT; mt++) {
      const int row = bm + wm + mt * 16 + quad * 4;
#pragma unroll
      for (int nt = 0; nt < 4; nt++) {
        const int col = bn + wn + nt * 16 + l16;
        float bval = 0.f;
        if (MODE & 2) bval = bias[col];
#pragma unroll
        for (int r = 0; r < 4; r++) {
          float v = acc[mt][nt][r] + bval;
          if (MODE & 1) v += R[(size_t)(row + r) * N + col];
          Cmat[(size_t)(row + r) * N + col] = (OutT)v;
        }
      }
    }
  }
}

// =====================  RMSNorm: fp32 in -> bf16 out (row = 1024)  =====================
__global__ __launch_bounds__(256) void rmsnorm_kernel(const float* __restrict__ X,
                                                      bf16* __restrict__ O) {
  const int row = blockIdx.x;
  const int tid = threadIdx.x;
  const int wave = tid >> 6;
  f32x4 v = *(const f32x4*)(X + (size_t)row * C_ + tid * 4);
  float s = v[0] * v[0] + v[1] * v[1] + v[2] * v[2] + v[3] * v[3];
#pragma unroll
  for (int off = 32; off >= 1; off >>= 1) s += __shfl_xor(s, off);
  __shared__ float wsum[4];
  __shared__ float scale_sh;
  if ((tid & 63) == 0) wsum[wave] = s;
  __syncthreads();
  if (tid == 0)
    scale_sh = rsqrtf((wsum[0] + wsum[1] + wsum[2] + wsum[3]) * (1.f / (float)C_) + 1e-6f);
  __syncthreads();
  const float sc = scale_sh;
  bf16x4 o;
  o[0] = (bf16)(v[0] * sc); o[1] = (bf16)(v[1] * sc);
  o[2] = (bf16)(v[2] * sc); o[3] = (bf16)(v[3] * sc);
  *(bf16x4*)(O + (size_t)row * C_ + tid * 4) = o;
}

// =====================  Hyperbolic flash attention (v8)  =====================
// 512-thread blocks, 128 q-rows each (8 waves x 16 rows), grid (B*H, 16): each
// K/V tile staged ONCE for 8 consuming waves. Staging crews: tid<256 stages K,
// tid>=256 stages V (packed b32 transpose). LDS double-buffer, single
// barrier/tile, register prefetch, LPT. Causal guard s0 <= tb+15.
__global__ __launch_bounds__(512) void attn_kernel(const bf16* __restrict__ qkv,
                                                   const float* __restrict__ q0b,
                                                   const float* __restrict__ k0b,
                                                   const float* __restrict__ kcb,
                                                   bf16* __restrict__ outp) {
  __shared__ __align__(16) bf16 Kls[2][64][72];
  __shared__ __align__(16) bf16 Vt[2][64][68];
  __shared__ __align__(16) bf16 Pls[8][16 * 36];
  __shared__ float k0s[2][64];

  const int tid = threadIdx.x;
  const int wave = tid >> 6, lane = tid & 63;
  const int quad = lane >> 4, l16 = lane & 15;
  const int bh = blockIdx.x;
  const int b = bh >> 4, h = bh & 15;

  const float kc = kcb[h];
  const float inv_kc = 1.f / kc;
  const float sqkc = SQRTF(kc);
  const int role = tid >> 8;            // 0: K crew, 1: V crew
  const int st = tid & 255;
  const int sp = st & 31, dq = st >> 5; // s-pair 0..31, d-chunk 0..7
  bf16* Pl = Pls[wave];
  const float* q0base = q0b + (size_t)(b * H_ + h) * T_;
  const float* k0base = k0b + (size_t)(b * H_ + h) * T_;

  const int ty = 15 - (int)blockIdx.y;   // heaviest blocks dispatch first
  const int t0 = ty * 128;
  const int tb = t0 + wave * 16;
  const int nIter = 2 * ty + 2;

  // q A-frags: A[m=l16][k=quad*8+j]
  const bf16* qrow = qkv + (size_t)(b * T_ + tb + l16) * 3072 + h * 64;
  bf16x8 aq0 = *(const bf16x8*)(qrow + quad * 8);
  bf16x8 aq1 = *(const bf16x8*)(qrow + 32 + quad * 8);
  float q0r[4];
#pragma unroll
  for (int r = 0; r < 4; r++) q0r[r] = q0base[tb + quad * 4 + r];

  f32x4 o[4];
#pragma unroll
  for (int dt = 0; dt < 4; dt++) o[dt] = f32x4{0.f, 0.f, 0.f, 0.f};
  float lrow[4] = {0.f, 0.f, 0.f, 0.f};

  // ---- prologue: prefetch tile 0.  role 0 loads K rows (2sp, 2sp+1); role 1 V.
  const bf16* base = qkv + (size_t)b * T_ * 3072 + 1024 + role * 1024 + h * 64 + dq * 8;
  bf16x8 pf_a = *(const bf16x8*)(base + (size_t)(2 * sp) * 3072);
  bf16x8 pf_b = *(const bf16x8*)(base + (size_t)(2 * sp + 1) * 3072);
  float k0v = (tid < 64) ? k0base[tid] : 0.f;

  for (int it = 0; it < nIter; ++it) {
    const int s0 = it * 64;
    const int buf = it & 1;
    if (role == 0) {
      *(bf16x8*)&Kls[buf][2 * sp][dq * 8]     = pf_a;
      *(bf16x8*)&Kls[buf][2 * sp + 1][dq * 8] = pf_b;
    } else {
#pragma unroll
      for (int i2 = 0; i2 < 8; i2++) {
        bf16x2 pr;
        pr[0] = pf_a[i2];
        pr[1] = pf_b[i2];
        *(bf16x2*)&Vt[buf][dq * 8 + i2][2 * sp] = pr;
      }
    }
    if (tid < 64) k0s[buf][tid] = k0v;
    __syncthreads();

    const int s0n = (it + 1 < nIter) ? s0 + 64 : s0;
    pf_a = *(const bf16x8*)(base + (size_t)(s0n + 2 * sp) * 3072);
    pf_b = *(const bf16x8*)(base + (size_t)(s0n + 2 * sp + 1) * 3072);
    if (tid < 64) k0v = k0base[s0n + tid];

    if (s0 <= tb + 15) {   // causal: this wave has live columns in the tile
      f32x4 sc[4];
#pragma unroll
      for (int nt = 0; nt < 4; nt++) {
        sc[nt] = f32x4{0.f, 0.f, 0.f, 0.f};
        bf16x8 b0 = *(const bf16x8*)&Kls[buf][nt * 16 + l16][quad * 8];
        bf16x8 b1 = *(const bf16x8*)&Kls[buf][nt * 16 + l16][32 + quad * 8];
        sc[nt] = __builtin_amdgcn_mfma_f32_16x16x32_bf16(aq0, b0, sc[nt], 0, 0, 0);
        sc[nt] = __builtin_amdgcn_mfma_f32_16x16x32_bf16(aq1, b1, sc[nt], 0, 0, 0);
      }

      bf16x8 ap[2];
#pragma unroll
      for (int ck = 0; ck < 2; ck++) {
#pragma unroll
        for (int ntl = 0; ntl < 2; ntl++) {
          const int nt = ck * 2 + ntl;
          const float k0c = k0s[buf][nt * 16 + l16];
          const int s = s0 + nt * 16 + l16;
#pragma unroll
          for (int r = 0; r < 4; r++) {
            const int t = tb + quad * 4 + r;
            float lor = sc[nt][r] - q0r[r] * k0c;
            float ratio = fmaxf(-lor * inv_kc, 1.f + 1e-6f);
            float wv = ratio + SQRTF(ratio * ratio - 1.f);
            float p = EXP2F(-sqkc * LOG2F(wv));
            p = (s <= t) ? p : 0.f;
            lrow[r] += p;
            Pl[(quad * 4 + r) * 36 + ntl * 16 + l16] = (bf16)p;
          }
        }
        ap[ck] = *(const bf16x8*)&Pl[l16 * 36 + quad * 8];
      }
#pragma unroll
      for (int dt = 0; dt < 4; dt++) {
        bf16x8 bv0 = *(const bf16x8*)&Vt[buf][dt * 16 + l16][quad * 8];
        bf16x8 bv1 = *(const bf16x8*)&Vt[buf][dt * 16 + l16][32 + quad * 8];
        o[dt] = __builtin_amdgcn_mfma_f32_16x16x32_bf16(ap[0], bv0, o[dt], 0, 0, 0);
        o[dt] = __builtin_amdgcn_mfma_f32_16x16x32_bf16(ap[1], bv1, o[dt], 0, 0, 0);
      }
    }
  }

#pragma unroll
  for (int r = 0; r < 4; r++) {
#pragma unroll
    for (int off = 1; off <= 8; off <<= 1) lrow[r] += __shfl_xor(lrow[r], off);
  }
#pragma unroll
  for (int r = 0; r < 4; r++) {
    const float invl = RCPF(lrow[r]);
    const int t = tb + quad * 4 + r;
#pragma unroll
    for (int dt = 0; dt < 4; dt++) {
      float val = o[dt][r] * invl;
      outp[(size_t)(b * T_ + t) * C_ + h * 64 + dt * 16 + l16] = (bf16)val;
    }
  }
}

// =====================  host-side launch  =====================
extern "C" void kernel_launch(void* const* d_in, const int* in_sizes, int n_in,
                              void* d_out, int out_size, void* d_ws, size_t ws_size,
                              hipStream_t stream) {
  const float* x      = (const float*)d_in[0];
  const float* w_qkv  = (const float*)d_in[1];
  const float* w_out  = (const float*)d_in[2];
  const float* kcb    = (const float*)d_in[3];
  const float* w_uv   = (const float*)d_in[4];
  const float* b_uv   = (const float*)d_in[5];
  const float* w_mlp  = (const float*)d_in[6];
  const float* b_mlp  = (const float*)d_in[7];
  float* out = (float*)d_out;

  const size_t MB = 1024ull * 1024ull;
  char* w = (char*)d_ws;
  bf16*  wqkv_b  = (bf16*)(w + 0);          //  6 MB   [0,6)
  bf16*  wout_b  = (bf16*)(w + 6 * MB);     //  2 MB   [6,8)
  bf16*  wuv_p   = (bf16*)(w + 8 * MB);     // 16 MB   [8,24)  row-permuted
  bf16*  wmlp_b  = (bf16*)(w + 24 * MB);    //  8 MB   [24,32)
  bf16*  hbuf    = (bf16*)(w + 32 * MB);    //  8 MB   [32,40)
  bf16*  qkvbuf  = (bf16*)(w + 40 * MB);    // 24 MB   [40,64) dead after attn
  bf16*  attnbuf = (bf16*)(w + 64 * MB);    //  8 MB   [64,72) dead after wout GEMM
  bf16*  gbuf    = (bf16*)(w + 40 * MB);    // 32 MB   [40,72) over qkv+attn (step 7)
  float* x2buf   = (float*)(w + 72 * MB);   // 16 MB   [72,88) fp32
  float* q0b     = (float*)(w + 88 * MB);                 // 256 KB
  float* k0b     = (float*)(w + 88 * MB + 256 * 1024);    // 256 KB
  float* biasp   = (float*)(w + 88 * MB + 512 * 1024);    //  32 KB (permuted b_uv)
  // total: ~88.6 MB

  // 0) weight casts (+w_uv/b_uv permutation) + rmsnorm#1 tail, single launch
  cast_rms_kernel<<<CAST_BLOCKS + M_, 256, 0, stream>>>(
      w_qkv, w_out, w_uv, w_mlp, b_uv, wqkv_b, wout_b, wuv_p, wmlp_b, biasp, x, hbuf);

  // 1) qkv = h @ w_qkv^T, rotary + q0/k0 fused in epilogue (MODE 5)
  gemm_bt<5, bf16><<<dim3(M_ / 128, 3072 / 128), 256, 0, stream>>>(
      hbuf, wqkv_b, qkvbuf, nullptr, nullptr, q0b, k0b, kcb, M_, 3072, 1024, 1024);
  // 2) hyperbolic flash attention (v8)
  attn_kernel<<<dim3(B_ * H_, 16), 512, 0, stream>>>(qkvbuf, q0b, k0b, kcb, attnbuf);
  // 3) x2 = x + attn @ w_out^T   (BM=64)
  gemm_bt<1, float, 64><<<dim3(M_ / 64, 1024 / 128), 256, 0, stream>>>(
      attnbuf, wout_b, x2buf, nullptr, x, nullptr, nullptr, nullptr, M_, 1024, 1024, 1024);
  // 4) h2 = rmsnorm(x2)
  rmsnorm_kernel<<<M_, 256, 0, stream>>>(x2buf, hbuf);
  // 5) g = swiglu(h2 @ w_uv_p^T + b_uv_p)  (MODE 4, register-only epilogue)
  gemm_bt<4, bf16><<<dim3(M_ / 128, 8192 / 128), 256, 0, stream>>>(
      hbuf, wuv_p, gbuf, biasp, nullptr, nullptr, nullptr, nullptr, M_, 4096, 1024, 1024);
  // 6) out = x2 + g @ w_mlp^T + b_mlp   (BM=64)
  gemm_bt<3, float, 64><<<dim3(M_ / 64, 1024 / 128), 256, 0, stream>>>(
      gbuf, wmlp_b, out, b_mlp, x2buf, nullptr, nullptr, nullptr, M_, 1024, 4096, 4096);
}